// Round 2
// baseline (166.273 us; speedup 1.0000x reference)
//
#include <hip/hip_runtime.h>
#include <stdint.h>

#define B_  4
#define T_  2048
#define C_  1024
#define D_  64

typedef float  f32x4  __attribute__((ext_vector_type(4)));
typedef float  f32x16 __attribute__((ext_vector_type(16)));
typedef short  s16x8  __attribute__((ext_vector_type(8)));

// softmax scale folded into Q-side weights/bias: 1/sqrt(64) * log2(e)
#define QSCALE 0.18033688011112042f

static __device__ __forceinline__ uint32_t f2bf(float f) {
  uint32_t u = __builtin_bit_cast(uint32_t, f);
  u += 0x7FFFu + ((u >> 16) & 1u);   // round-to-nearest-even
  return u >> 16;
}
static __device__ __forceinline__ uint32_t pack2bf(float a, float b) {
  return f2bf(a) | (f2bf(b) << 16);
}
static __device__ __forceinline__ s16x8 pack8bf(float4 a, float4 b) {
  union { uint32_t u[4]; s16x8 v; } cv;
  cv.u[0] = pack2bf(a.x, a.y);
  cv.u[1] = pack2bf(a.z, a.w);
  cv.u[2] = pack2bf(b.x, b.y);
  cv.u[3] = pack2bf(b.z, b.w);
  return cv.v;
}

// ---------------------------------------------------------------------------
// Kernel 1: W pack. Coalesced float4 row reads; scattered 2B writes (stores
// are fire-and-forget). WcatT bf16 [192][1024] (row n = output col, c-contig).
// ---------------------------------------------------------------------------
__global__ __launch_bounds__(256) void wconv_kernel(
    const float* __restrict__ Wq, const float* __restrict__ bq,
    const float* __restrict__ Wk, const float* __restrict__ bk,
    const float* __restrict__ Wv, const float* __restrict__ bv,
    uint16_t* __restrict__ WcatT, float* __restrict__ biascat) {
  const int gid = blockIdx.x * 256 + threadIdx.x;  // 0..49151
  const int mat = gid >> 14;                        // 16384 float4 per matrix
  const int rem = gid & 16383;
  const int c   = rem >> 4;
  const int n0  = (rem & 15) << 2;
  const float* W = (mat == 0) ? Wq : ((mat == 1) ? Wk : Wv);
  const float  s = (mat == 0) ? QSCALE : 1.0f;
  float4 w = *reinterpret_cast<const float4*>(W + (size_t)c * D_ + n0);
  WcatT[(size_t)(mat * 64 + n0 + 0) * C_ + c] = (uint16_t)f2bf(w.x * s);
  WcatT[(size_t)(mat * 64 + n0 + 1) * C_ + c] = (uint16_t)f2bf(w.y * s);
  WcatT[(size_t)(mat * 64 + n0 + 2) * C_ + c] = (uint16_t)f2bf(w.z * s);
  WcatT[(size_t)(mat * 64 + n0 + 3) * C_ + c] = (uint16_t)f2bf(w.w * s);
  if (gid < 192) {
    float bb;
    if (gid < 64)       bb = bq[gid] * QSCALE;
    else if (gid < 128) bb = bk[gid - 64];
    else                bb = bv[gid - 128];
    biascat[gid] = bb;
  }
}

// ---------------------------------------------------------------------------
// Kernel 2: QKV projection (verified MFMA mapping from R1, m-tile halved).
// 512 blocks x 16 rows -> 2 blocks/CU, unroll-4 keeps ~20 loads in flight.
// ---------------------------------------------------------------------------
__global__ __launch_bounds__(256) void proj_kernel(
    const float* __restrict__ x, const uint16_t* __restrict__ WcatT,
    const float* __restrict__ biascat,
    uint16_t* __restrict__ Qbf, uint16_t* __restrict__ Kbf,
    uint16_t* __restrict__ Vt) {
  __shared__ __align__(16) uint16_t tbuf[4][16 * 28];
  const int tid  = threadIdx.x;
  const int wave = tid >> 6;
  const int lane = tid & 63;
  const int mrow = lane & 15;
  const int u    = lane >> 4;
  const int m0   = blockIdx.x * 16;

  const float*    xr = x + (size_t)(m0 + mrow) * C_ + u * 8;
  const uint16_t* wb = WcatT + (size_t)(wave * 48 + mrow) * C_ + u * 8;

  f32x4 acc[3];
#pragma unroll
  for (int i = 0; i < 3; ++i)
#pragma unroll
    for (int r = 0; r < 4; ++r) acc[i][r] = 0.f;

#pragma unroll 4
  for (int s = 0; s < 32; ++s) {
    const int cb = s * 32;
    float4 a0 = *reinterpret_cast<const float4*>(xr + cb);
    float4 a1 = *reinterpret_cast<const float4*>(xr + cb + 4);
    s16x8 af0 = *reinterpret_cast<const s16x8*>(wb + cb);
    s16x8 af1 = *reinterpret_cast<const s16x8*>(wb + (size_t)16 * C_ + cb);
    s16x8 af2 = *reinterpret_cast<const s16x8*>(wb + (size_t)32 * C_ + cb);
    s16x8 xf = pack8bf(a0, a1);
    acc[0] = __builtin_amdgcn_mfma_f32_16x16x32_bf16(af0, xf, acc[0], 0, 0, 0);
    acc[1] = __builtin_amdgcn_mfma_f32_16x16x32_bf16(af1, xf, acc[1], 0, 0, 0);
    acc[2] = __builtin_amdgcn_mfma_f32_16x16x32_bf16(af2, xf, acc[2], 0, 0, 0);
  }

  const int bb  = m0 >> 11;        // batch
  const int tt0 = m0 & (T_ - 1);   // t offset within batch
#pragma unroll
  for (int nt = 0; nt < 3; ++nt) {
    const int nb = wave * 48 + nt * 16;
    uint16_t vals[4];
#pragma unroll
    for (int r = 0; r < 4; ++r)
      vals[r] = (uint16_t)f2bf(acc[nt][r] + biascat[nb + u * 4 + r]);
    if (nb >= 128) {
      // V: store directly transposed Vt[b][d][t]
#pragma unroll
      for (int r = 0; r < 4; ++r) {
        int vrow = nb - 128 + u * 4 + r;
        Vt[((size_t)bb * D_ + vrow) * T_ + tt0 + mrow] = vals[r];
      }
    } else {
      // Q/K: per-wave LDS transpose, then 8B coalesced-ish stores
#pragma unroll
      for (int r = 0; r < 4; ++r)
        tbuf[wave][mrow * 28 + u * 4 + r] = vals[r];
      const int row = lane >> 2, qtr = lane & 3;
      uint2 v = *reinterpret_cast<const uint2*>(&tbuf[wave][row * 28 + qtr * 4]);
      uint16_t* dst = (nb < 64) ? (Qbf + nb) : (Kbf + (nb - 64));
      *reinterpret_cast<uint2*>(dst + (size_t)(m0 + row) * D_ + qtr * 4) = v;
    }
  }
}

// ---------------------------------------------------------------------------
// Kernel 3: attention, balanced block-jobs. Job = (b, qt, chunk of 16 k-tiles)
// -> 160 jobs/batch, 640 blocks. 4 waves stride the chunk (<=4 serial steps),
// LDS-merge, write one fp32 partial [32q][64d] + l[32] per job.
// MFMA fragment mappings inherited verbatim from the R1-verified kernel.
// ---------------------------------------------------------------------------
__global__ __launch_bounds__(256) void attn_kernel(
    const uint16_t* __restrict__ Qbf, const uint16_t* __restrict__ Kbf,
    const uint16_t* __restrict__ Vt, float* __restrict__ partial,
    float* __restrict__ lpart) {
  __shared__ __align__(16) uint16_t plds[4][32 * 40];
  __shared__ float obuf[64 * 33];
  __shared__ float lbuf[32];

  const int tid  = threadIdx.x;
  const int wave = tid >> 6;
  const int lane = tid & 63;
  const int ql   = lane & 31;
  const int hi   = lane >> 5;

  // block -> (batch pinned to XCD pair, job j in [0,160))
  const int blk = blockIdx.x;
  const int b   = (blk & 7) >> 1;
  const int j   = 2 * (blk >> 3) + (blk & 1);

  // decode j -> (qt, chunk): qt = 16a + r has a+1 chunks;
  // group a occupies [8a(a+1), 8(a+1)(a+2))
  int a_ = 0;
  while (8 * (a_ + 1) * (a_ + 2) <= j) ++a_;
  const int off = j - 8 * a_ * (a_ + 1);
  const int r_  = off / (a_ + 1);
  const int ch  = off - r_ * (a_ + 1);
  const int qt  = 16 * a_ + r_;
  const int c16 = ch * 16;
  const int qb  = qt * 32;
  const int tmax = min(c16 + 15, qt);
  const int pj  = b * 160 + j;

  const uint16_t* Qb = Qbf + (size_t)b * T_ * D_;
  const uint16_t* Kb = Kbf + (size_t)b * T_ * D_;
  const uint16_t* Vb = Vt + (size_t)b * D_ * T_;

  s16x8 qf[4];
#pragma unroll
  for (int c = 0; c < 4; ++c)
    qf[c] = *reinterpret_cast<const s16x8*>(Qb + (size_t)(qb + ql) * D_ + c * 16 + hi * 8);

  f32x16 aco[2];
#pragma unroll
  for (int i = 0; i < 2; ++i)
#pragma unroll
    for (int r = 0; r < 16; ++r) aco[i][r] = 0.f;
  float lacc = 0.f;

  for (int t = c16 + wave; t <= tmax; t += 4) {
    const int kb = t * 32;
    // issue all loads up front; vf stays in flight through S+exp2
    s16x8 kf[4], vf[2][2];
#pragma unroll
    for (int c = 0; c < 4; ++c)
      kf[c] = *reinterpret_cast<const s16x8*>(Kb + (size_t)(kb + ql) * D_ + c * 16 + hi * 8);
#pragma unroll
    for (int dm = 0; dm < 2; ++dm)
#pragma unroll
      for (int kc = 0; kc < 2; ++kc)
        vf[dm][kc] = *reinterpret_cast<const s16x8*>(
            Vb + (size_t)(dm * 32 + ql) * T_ + kb + kc * 16 + hi * 8);

    f32x16 sacc;
#pragma unroll
    for (int r = 0; r < 16; ++r) sacc[r] = 0.f;
#pragma unroll
    for (int c = 0; c < 4; ++c)
      sacc = __builtin_amdgcn_mfma_f32_32x32x16_bf16(kf[c], qf[c], sacc, 0, 0, 0);

    if (t == qt) {  // diagonal tile: causal mask
#pragma unroll
      for (int r = 0; r < 16; ++r) {
        const int koff = (r & 3) + 8 * (r >> 2) + 4 * hi;
        sacc[r] = (koff > ql) ? -1e30f : sacc[r];
      }
    }
    float p[16];
#pragma unroll
    for (int r = 0; r < 16; ++r) p[r] = __builtin_amdgcn_exp2f(sacc[r]);
    float s01 = (p[0] + p[1]) + (p[2] + p[3]);
    float s23 = (p[4] + p[5]) + (p[6] + p[7]);
    float s45 = (p[8] + p[9]) + (p[10] + p[11]);
    float s67 = (p[12] + p[13]) + (p[14] + p[15]);
    lacc += (s01 + s23) + (s45 + s67);

    // P: C-layout -> A-layout via per-wave LDS (verified R1 pattern)
#pragma unroll
    for (int g = 0; g < 4; ++g) {
      uint2 w;
      w.x = pack2bf(p[4 * g + 0], p[4 * g + 1]);
      w.y = pack2bf(p[4 * g + 2], p[4 * g + 3]);
      *reinterpret_cast<uint2*>(&plds[wave][ql * 40 + 8 * g + 4 * hi]) = w;
    }
#pragma unroll
    for (int kc = 0; kc < 2; ++kc) {
      s16x8 pf = *reinterpret_cast<const s16x8*>(&plds[wave][ql * 40 + kc * 16 + hi * 8]);
      aco[0] = __builtin_amdgcn_mfma_f32_32x32x16_bf16(vf[0][kc], pf, aco[0], 0, 0, 0);
      aco[1] = __builtin_amdgcn_mfma_f32_32x32x16_bf16(vf[1][kc], pf, aco[1], 0, 0, 0);
    }
  }

  lacc += __shfl_xor(lacc, 32, 64);

  for (int i = tid; i < 64 * 33; i += 256) obuf[i] = 0.f;
  if (tid < 32) lbuf[tid] = 0.f;
  __syncthreads();

  if (hi == 0) atomicAdd(&lbuf[ql], lacc);
#pragma unroll
  for (int dm = 0; dm < 2; ++dm)
#pragma unroll
    for (int r = 0; r < 16; ++r) {
      const int d = dm * 32 + (r & 3) + 8 * (r >> 2) + 4 * hi;
      atomicAdd(&obuf[d * 33 + ql], aco[dm][r]);
    }
  __syncthreads();

  // one coalesced 8KB partial per block, [q][d] layout
  const int q  = tid >> 3;
  const int dg = (tid & 7) * 8;
  float4 o0, o1;
  o0.x = obuf[(dg + 0) * 33 + q];
  o0.y = obuf[(dg + 1) * 33 + q];
  o0.z = obuf[(dg + 2) * 33 + q];
  o0.w = obuf[(dg + 3) * 33 + q];
  o1.x = obuf[(dg + 4) * 33 + q];
  o1.y = obuf[(dg + 5) * 33 + q];
  o1.z = obuf[(dg + 6) * 33 + q];
  o1.w = obuf[(dg + 7) * 33 + q];
  float* pp = partial + (size_t)pj * 2048 + tid * 8;
  *reinterpret_cast<float4*>(pp)     = o0;
  *reinterpret_cast<float4*>(pp + 4) = o1;
  if (tid < 32) lpart[(size_t)pj * 32 + tid] = lbuf[tid];
}

// ---------------------------------------------------------------------------
// Kernel 4: reduce partials (<=4 per q-tile), normalize, write out fp32.
// ---------------------------------------------------------------------------
__global__ __launch_bounds__(256) void reduce_kernel(
    const float* __restrict__ partial, const float* __restrict__ lpart,
    float* __restrict__ out) {
  __shared__ float lbuf[32];
  const int blk = blockIdx.x;          // 256 = 4 b x 64 qt
  const int b   = blk >> 6;
  const int qt  = blk & 63;
  const int a_  = qt >> 4;
  const int nch = a_ + 1;
  const int pjb = b * 160 + 8 * a_ * (a_ + 1) + (qt & 15) * (a_ + 1);
  const int t   = threadIdx.x;

  float4 acc0 = {0.f, 0.f, 0.f, 0.f}, acc1 = {0.f, 0.f, 0.f, 0.f};
  for (int c = 0; c < nch; ++c) {
    const float* p = partial + (size_t)(pjb + c) * 2048 + t * 8;
    float4 u0 = *reinterpret_cast<const float4*>(p);
    float4 u1 = *reinterpret_cast<const float4*>(p + 4);
    acc0.x += u0.x; acc0.y += u0.y; acc0.z += u0.z; acc0.w += u0.w;
    acc1.x += u1.x; acc1.y += u1.y; acc1.z += u1.z; acc1.w += u1.w;
  }
  if (t < 32) {
    float s = 0.f;
    for (int c = 0; c < nch; ++c) s += lpart[(size_t)(pjb + c) * 32 + t];
    lbuf[t] = s;
  }
  __syncthreads();
  const float rinv = 1.0f / lbuf[t >> 3];
  acc0.x *= rinv; acc0.y *= rinv; acc0.z *= rinv; acc0.w *= rinv;
  acc1.x *= rinv; acc1.y *= rinv; acc1.z *= rinv; acc1.w *= rinv;
  float* op = out + ((size_t)(b * T_ + qt * 32 + (t >> 3))) * D_ + (t & 7) * 8;
  *reinterpret_cast<float4*>(op)     = acc0;
  *reinterpret_cast<float4*>(op + 4) = acc1;
}

// ---------------------------------------------------------------------------
extern "C" void kernel_launch(void* const* d_in, const int* in_sizes, int n_in,
                              void* d_out, int out_size, void* d_ws, size_t ws_size,
                              hipStream_t stream) {
  (void)in_sizes; (void)n_in; (void)out_size; (void)ws_size;
  const float* x  = (const float*)d_in[0];
  const float* Wq = (const float*)d_in[1];
  const float* bq = (const float*)d_in[2];
  const float* Wk = (const float*)d_in[3];
  const float* bk = (const float*)d_in[4];
  const float* Wv = (const float*)d_in[5];
  const float* bv = (const float*)d_in[6];
  float* out = (float*)d_out;

  char* ws = (char*)d_ws;
  uint16_t* WcatT   = (uint16_t*)(ws);                 // 393,216 B
  float*    biascat = (float*)(ws + 393216);           // 1,024 B (768 used)
  uint16_t* Qbf     = (uint16_t*)(ws + 394240);        // 1,048,576 B
  uint16_t* Kbf     = (uint16_t*)(ws + 1442816);       // 1,048,576 B
  uint16_t* Vt      = (uint16_t*)(ws + 2491392);       // 1,048,576 B
  float*    partial = (float*)(ws + 3539968);          // 5,242,880 B
  float*    lpart   = (float*)(ws + 8782848);          // 81,920 B

  hipLaunchKernelGGL(wconv_kernel, dim3(192), dim3(256), 0, stream,
                     Wq, bq, Wk, bk, Wv, bv, WcatT, biascat);
  hipLaunchKernelGGL(proj_kernel, dim3(512), dim3(256), 0, stream,
                     x, WcatT, biascat, Qbf, Kbf, Vt);
  hipLaunchKernelGGL(attn_kernel, dim3(640), dim3(256), 0, stream,
                     Qbf, Kbf, Vt, partial, lpart);
  hipLaunchKernelGGL(reduce_kernel, dim3(256), dim3(256), 0, stream,
                     partial, lpart, out);
}

// Round 3
// 144.179 us; speedup vs baseline: 1.1532x; 1.1532x over previous
//
#include <hip/hip_runtime.h>
#include <stdint.h>

#define B_  4
#define T_  2048
#define C_  1024
#define D_  64

typedef float  f32x4  __attribute__((ext_vector_type(4)));
typedef float  f32x16 __attribute__((ext_vector_type(16)));
typedef short  s16x8  __attribute__((ext_vector_type(8)));

// softmax scale folded into Q-side weights/bias: 1/sqrt(64) * log2(e)
#define QSCALE 0.18033688011112042f

static __device__ __forceinline__ uint32_t f2bf(float f) {
  uint32_t u = __builtin_bit_cast(uint32_t, f);
  u += 0x7FFFu + ((u >> 16) & 1u);   // round-to-nearest-even
  return u >> 16;
}
static __device__ __forceinline__ uint32_t pack2bf(float a, float b) {
  return f2bf(a) | (f2bf(b) << 16);
}

// ---------------------------------------------------------------------------
// Kernel 1: pack W into MFMA-A-fragment order.
// Wp[g*8..g*8+7] where g = (s32*12 + ntile)*64 + lane holds
// WcatT[n = ntile*16 + (lane&15)][c = s32*32 + (lane>>4)*8 + j], j=0..7.
// => proj reads A-frags as wave-contiguous 16B/lane (perfectly coalesced).
// ---------------------------------------------------------------------------
__global__ __launch_bounds__(256) void wconv_kernel(
    const float* __restrict__ Wq, const float* __restrict__ bq,
    const float* __restrict__ Wk, const float* __restrict__ bk,
    const float* __restrict__ Wv, const float* __restrict__ bv,
    uint16_t* __restrict__ Wp, float* __restrict__ biascat) {
  const int g = blockIdx.x * 256 + threadIdx.x;  // 0..24575
  const int s32   = g / 768;
  const int rem   = g - s32 * 768;
  const int ntile = rem >> 6;
  const int l     = rem & 63;
  const int mrow  = l & 15, u = l >> 4;
  const int n     = ntile * 16 + mrow;
  const int mat   = n >> 6, col = n & 63;
  const float* W  = (mat == 0) ? Wq : ((mat == 1) ? Wk : Wv);
  const float  s  = (mat == 0) ? QSCALE : 1.0f;
  const int c0    = s32 * 32 + u * 8;
  float v[8];
#pragma unroll
  for (int j = 0; j < 8; ++j) v[j] = W[(size_t)(c0 + j) * D_ + col] * s;
  uint4 st;
  st.x = pack2bf(v[0], v[1]);
  st.y = pack2bf(v[2], v[3]);
  st.z = pack2bf(v[4], v[5]);
  st.w = pack2bf(v[6], v[7]);
  *reinterpret_cast<uint4*>(Wp + (size_t)g * 8) = st;
  if (g < 192) {
    float bb;
    if (g < 64)       bb = bq[g] * QSCALE;
    else if (g < 128) bb = bk[g - 64];
    else              bb = bv[g - 128];
    biascat[g] = bb;
  }
}

// ---------------------------------------------------------------------------
// Kernel 2: QKV projection. 512 blocks x BM=16 rows. x staged to LDS with
// coalesced float4 loads (pad-66 rows -> <=2-way-conflict ds_read_b128);
// W A-frags stream coalesced from Wp (L2-resident). MFMA mapping = R1/R2
// verified. V written tiled: Vtile[b][t32][64d][32t] (4KB-contig tiles).
// ---------------------------------------------------------------------------
__global__ __launch_bounds__(256) void proj_kernel(
    const float* __restrict__ x, const uint16_t* __restrict__ Wp,
    const float* __restrict__ biascat,
    uint16_t* __restrict__ Qbf, uint16_t* __restrict__ Kbf,
    uint16_t* __restrict__ Vtile) {
  __shared__ __align__(16) uint16_t xt[16 * 66];
  __shared__ __align__(16) uint16_t tbuf[4][16 * 28];
  const int tid  = threadIdx.x;
  const int wave = tid >> 6;
  const int lane = tid & 63;
  const int mrow = lane & 15;
  const int u    = lane >> 4;
  const int m0   = blockIdx.x * 16;
  const int srow = tid >> 4, scol = tid & 15;

  const float* xg = x + (size_t)(m0 + srow) * C_ + scol * 4;

  f32x4 acc[3];
#pragma unroll
  for (int i = 0; i < 3; ++i)
#pragma unroll
    for (int r = 0; r < 4; ++r) acc[i][r] = 0.f;

  for (int s = 0; s < 16; ++s) {
    float4 xv = *reinterpret_cast<const float4*>(xg + s * 64);
    uint2 w2;
    w2.x = pack2bf(xv.x, xv.y);
    w2.y = pack2bf(xv.z, xv.w);
    __syncthreads();  // previous iter's frag reads done before overwrite
    *reinterpret_cast<uint2*>(&xt[srow * 66 + scol * 4]) = w2;
    __syncthreads();
#pragma unroll
    for (int step = 0; step < 2; ++step) {
      const int s32 = s * 2 + step;
      s16x8 bf = *reinterpret_cast<const s16x8*>(&xt[mrow * 66 + step * 32 + u * 8]);
      const uint16_t* wb = Wp + ((size_t)(s32 * 12 + wave * 3) * 64 + lane) * 8;
      s16x8 a0 = *reinterpret_cast<const s16x8*>(wb);
      s16x8 a1 = *reinterpret_cast<const s16x8*>(wb + 64 * 8);
      s16x8 a2 = *reinterpret_cast<const s16x8*>(wb + 128 * 8);
      acc[0] = __builtin_amdgcn_mfma_f32_16x16x32_bf16(a0, bf, acc[0], 0, 0, 0);
      acc[1] = __builtin_amdgcn_mfma_f32_16x16x32_bf16(a1, bf, acc[1], 0, 0, 0);
      acc[2] = __builtin_amdgcn_mfma_f32_16x16x32_bf16(a2, bf, acc[2], 0, 0, 0);
    }
  }

  const int bb  = m0 >> 11;        // batch
  const int mm  = m0 & (T_ - 1);   // t offset within batch
#pragma unroll
  for (int nt = 0; nt < 3; ++nt) {
    const int nb = wave * 48 + nt * 16;
    uint16_t vals[4];
#pragma unroll
    for (int r = 0; r < 4; ++r)
      vals[r] = (uint16_t)f2bf(acc[nt][r] + biascat[nb + u * 4 + r]);
    if (nb >= 128) {
      // V -> tiled layout [b][t32][d][32t]
      const int tl   = mm >> 5;
      const int toff = (mm & 31) + mrow;
#pragma unroll
      for (int r = 0; r < 4; ++r) {
        int vrow = nb - 128 + u * 4 + r;
        Vtile[(((size_t)bb * 64 + tl) * 64 + vrow) * 32 + toff] = vals[r];
      }
    } else {
      // Q/K: per-wave LDS transpose, then 8B stores
#pragma unroll
      for (int r = 0; r < 4; ++r)
        tbuf[wave][mrow * 28 + u * 4 + r] = vals[r];
      const int row = lane >> 2, qtr = lane & 3;
      uint2 v = *reinterpret_cast<const uint2*>(&tbuf[wave][row * 28 + qtr * 4]);
      uint16_t* dst = (nb < 64) ? (Qbf + nb) : (Kbf + (nb - 64));
      *reinterpret_cast<uint2*>(dst + (size_t)(m0 + row) * D_ + qtr * 4) = v;
    }
  }
}

// ---------------------------------------------------------------------------
// Kernel 3: attention. Balanced jobs (R2-verified decode). Per-wave k-loop:
// coalesced 16B/lane stage of K-tile (4KB contig in Kbf) and V-tile (4KB
// contig in Vtile) into padded per-wave LDS; all MFMA frags via ds_read_b128
// (<=2-way bank aliasing). No barriers in the k-loop.
// ---------------------------------------------------------------------------
__global__ __launch_bounds__(256) void attn_kernel(
    const uint16_t* __restrict__ Qbf, const uint16_t* __restrict__ Kbf,
    const uint16_t* __restrict__ Vtile, float* __restrict__ partial,
    float* __restrict__ lpart) {
  __shared__ __align__(16) uint16_t qt_[32 * 66];       // 4224 B
  __shared__ __align__(16) uint16_t kt_[4][32 * 66];    // 16896 B
  __shared__ __align__(16) uint16_t vt_[4][64 * 34];    // 17408 B
  __shared__ __align__(16) uint16_t plds[4][32 * 40];   // 10240 B
  __shared__ float obuf[64 * 33];                       // 8448 B
  __shared__ float lbuf[32];

  const int tid  = threadIdx.x;
  const int wave = tid >> 6;
  const int lane = tid & 63;
  const int ql   = lane & 31;
  const int hi   = lane >> 5;

  const int blk = blockIdx.x;
  const int b   = (blk & 7) >> 1;
  const int j   = 2 * (blk >> 3) + (blk & 1);

  int a_ = 0;
  while (8 * (a_ + 1) * (a_ + 2) <= j) ++a_;
  const int off = j - 8 * a_ * (a_ + 1);
  const int r_  = off / (a_ + 1);
  const int ch  = off - r_ * (a_ + 1);
  const int qt  = 16 * a_ + r_;
  const int c16 = ch * 16;
  const int qb  = qt * 32;
  const int tmax = min(c16 + 15, qt);
  const int pj  = b * 160 + j;

  const uint16_t* Qb = Qbf + (size_t)b * T_ * D_;
  const uint16_t* Kb = Kbf + (size_t)b * T_ * D_;

  // stage Q-tile (4KB contiguous) cooperatively, padded rows of 66
  {
    uint4 qv = *reinterpret_cast<const uint4*>(Qb + (size_t)qb * D_ + tid * 8);
    *reinterpret_cast<uint4*>(&qt_[(tid >> 3) * 66 + (tid & 7) * 8]) = qv;
  }
  __syncthreads();

  s16x8 qf[4];
#pragma unroll
  for (int c = 0; c < 4; ++c)
    qf[c] = *reinterpret_cast<const s16x8*>(&qt_[ql * 66 + c * 16 + hi * 8]);

  f32x16 aco[2];
#pragma unroll
  for (int i = 0; i < 2; ++i)
#pragma unroll
    for (int r = 0; r < 16; ++r) aco[i][r] = 0.f;
  float lacc = 0.f;

  for (int t = c16 + wave; t <= tmax; t += 4) {
    // coalesced stage: K-tile rows [32t][64d], V-tile rows [64d][32t]
    const uint16_t* kg = Kb + (size_t)(t * 32) * D_;
    const uint16_t* vg = Vtile + ((size_t)(b * 64 + t) * 64) * 32;
    uint4 kv[4], vv[4];
#pragma unroll
    for (int jj = 0; jj < 4; ++jj)
      kv[jj] = *reinterpret_cast<const uint4*>(kg + jj * 512 + lane * 8);
#pragma unroll
    for (int jj = 0; jj < 4; ++jj)
      vv[jj] = *reinterpret_cast<const uint4*>(vg + jj * 512 + lane * 8);
#pragma unroll
    for (int jj = 0; jj < 4; ++jj)
      *reinterpret_cast<uint4*>(
          &kt_[wave][(8 * jj + (lane >> 3)) * 66 + (lane & 7) * 8]) = kv[jj];
#pragma unroll
    for (int jj = 0; jj < 4; ++jj)
      *reinterpret_cast<uint4*>(
          &vt_[wave][(16 * jj + (lane >> 2)) * 34 + (lane & 3) * 8]) = vv[jj];

    f32x16 sacc;
#pragma unroll
    for (int r = 0; r < 16; ++r) sacc[r] = 0.f;
#pragma unroll
    for (int c = 0; c < 4; ++c) {
      s16x8 kf = *reinterpret_cast<const s16x8*>(&kt_[wave][ql * 66 + c * 16 + hi * 8]);
      sacc = __builtin_amdgcn_mfma_f32_32x32x16_bf16(kf, qf[c], sacc, 0, 0, 0);
    }

    if (t == qt) {  // diagonal tile: causal mask
#pragma unroll
      for (int r = 0; r < 16; ++r) {
        const int koff = (r & 3) + 8 * (r >> 2) + 4 * hi;
        sacc[r] = (koff > ql) ? -1e30f : sacc[r];
      }
    }
    float p[16];
#pragma unroll
    for (int r = 0; r < 16; ++r) p[r] = __builtin_amdgcn_exp2f(sacc[r]);
    float s01 = (p[0] + p[1]) + (p[2] + p[3]);
    float s23 = (p[4] + p[5]) + (p[6] + p[7]);
    float s45 = (p[8] + p[9]) + (p[10] + p[11]);
    float s67 = (p[12] + p[13]) + (p[14] + p[15]);
    lacc += (s01 + s23) + (s45 + s67);

    // P: C-layout -> A-layout via per-wave LDS (R1/R2-verified)
#pragma unroll
    for (int g = 0; g < 4; ++g) {
      uint2 w;
      w.x = pack2bf(p[4 * g + 0], p[4 * g + 1]);
      w.y = pack2bf(p[4 * g + 2], p[4 * g + 3]);
      *reinterpret_cast<uint2*>(&plds[wave][ql * 40 + 8 * g + 4 * hi]) = w;
    }
#pragma unroll
    for (int kc = 0; kc < 2; ++kc) {
      s16x8 pf = *reinterpret_cast<const s16x8*>(&plds[wave][ql * 40 + kc * 16 + hi * 8]);
#pragma unroll
      for (int dm = 0; dm < 2; ++dm) {
        s16x8 vf = *reinterpret_cast<const s16x8*>(
            &vt_[wave][(dm * 32 + ql) * 34 + kc * 16 + hi * 8]);
        aco[dm] = __builtin_amdgcn_mfma_f32_32x32x16_bf16(vf, pf, aco[dm], 0, 0, 0);
      }
    }
  }

  lacc += __shfl_xor(lacc, 32, 64);

  for (int i = tid; i < 64 * 33; i += 256) obuf[i] = 0.f;
  if (tid < 32) lbuf[tid] = 0.f;
  __syncthreads();

  if (hi == 0) atomicAdd(&lbuf[ql], lacc);
#pragma unroll
  for (int dm = 0; dm < 2; ++dm)
#pragma unroll
    for (int r = 0; r < 16; ++r) {
      const int d = dm * 32 + (r & 3) + 8 * (r >> 2) + 4 * hi;
      atomicAdd(&obuf[d * 33 + ql], aco[dm][r]);
    }
  __syncthreads();

  const int q  = tid >> 3;
  const int dg = (tid & 7) * 8;
  float4 o0, o1;
  o0.x = obuf[(dg + 0) * 33 + q];
  o0.y = obuf[(dg + 1) * 33 + q];
  o0.z = obuf[(dg + 2) * 33 + q];
  o0.w = obuf[(dg + 3) * 33 + q];
  o1.x = obuf[(dg + 4) * 33 + q];
  o1.y = obuf[(dg + 5) * 33 + q];
  o1.z = obuf[(dg + 6) * 33 + q];
  o1.w = obuf[(dg + 7) * 33 + q];
  float* pp = partial + (size_t)pj * 2048 + tid * 8;
  *reinterpret_cast<float4*>(pp)     = o0;
  *reinterpret_cast<float4*>(pp + 4) = o1;
  if (tid < 32) lpart[(size_t)pj * 32 + tid] = lbuf[tid];
}

// ---------------------------------------------------------------------------
// Kernel 4: reduce partials (<=4 per q-tile), normalize, write out fp32.
// ---------------------------------------------------------------------------
__global__ __launch_bounds__(256) void reduce_kernel(
    const float* __restrict__ partial, const float* __restrict__ lpart,
    float* __restrict__ out) {
  __shared__ float lbuf[32];
  const int blk = blockIdx.x;          // 256 = 4 b x 64 qt
  const int b   = blk >> 6;
  const int qt  = blk & 63;
  const int a_  = qt >> 4;
  const int nch = a_ + 1;
  const int pjb = b * 160 + 8 * a_ * (a_ + 1) + (qt & 15) * (a_ + 1);
  const int t   = threadIdx.x;

  float4 acc0 = {0.f, 0.f, 0.f, 0.f}, acc1 = {0.f, 0.f, 0.f, 0.f};
  for (int c = 0; c < nch; ++c) {
    const float* p = partial + (size_t)(pjb + c) * 2048 + t * 8;
    float4 u0 = *reinterpret_cast<const float4*>(p);
    float4 u1 = *reinterpret_cast<const float4*>(p + 4);
    acc0.x += u0.x; acc0.y += u0.y; acc0.z += u0.z; acc0.w += u0.w;
    acc1.x += u1.x; acc1.y += u1.y; acc1.z += u1.z; acc1.w += u1.w;
  }
  if (t < 32) {
    float s = 0.f;
    for (int c = 0; c < nch; ++c) s += lpart[(size_t)(pjb + c) * 32 + t];
    lbuf[t] = s;
  }
  __syncthreads();
  const float rinv = 1.0f / lbuf[t >> 3];
  acc0.x *= rinv; acc0.y *= rinv; acc0.z *= rinv; acc0.w *= rinv;
  acc1.x *= rinv; acc1.y *= rinv; acc1.z *= rinv; acc1.w *= rinv;
  float* op = out + ((size_t)(b * T_ + qt * 32 + (t >> 3))) * D_ + (t & 7) * 8;
  *reinterpret_cast<float4*>(op)     = acc0;
  *reinterpret_cast<float4*>(op + 4) = acc1;
}

// ---------------------------------------------------------------------------
extern "C" void kernel_launch(void* const* d_in, const int* in_sizes, int n_in,
                              void* d_out, int out_size, void* d_ws, size_t ws_size,
                              hipStream_t stream) {
  (void)in_sizes; (void)n_in; (void)out_size; (void)ws_size;
  const float* x  = (const float*)d_in[0];
  const float* Wq = (const float*)d_in[1];
  const float* bq = (const float*)d_in[2];
  const float* Wk = (const float*)d_in[3];
  const float* bk = (const float*)d_in[4];
  const float* Wv = (const float*)d_in[5];
  const float* bv = (const float*)d_in[6];
  float* out = (float*)d_out;

  char* ws = (char*)d_ws;
  uint16_t* Wp      = (uint16_t*)(ws);                 // 393,216 B
  float*    biascat = (float*)(ws + 393216);           // 1,024 B (768 used)
  uint16_t* Qbf     = (uint16_t*)(ws + 394240);        // 1,048,576 B
  uint16_t* Kbf     = (uint16_t*)(ws + 1442816);       // 1,048,576 B
  uint16_t* Vtile   = (uint16_t*)(ws + 2491392);       // 1,048,576 B
  float*    partial = (float*)(ws + 3539968);          // 5,242,880 B
  float*    lpart   = (float*)(ws + 8782848);          // 81,920 B

  hipLaunchKernelGGL(wconv_kernel, dim3(96), dim3(256), 0, stream,
                     Wq, bq, Wk, bk, Wv, bv, Wp, biascat);
  hipLaunchKernelGGL(proj_kernel, dim3(512), dim3(256), 0, stream,
                     x, Wp, biascat, Qbf, Kbf, Vtile);
  hipLaunchKernelGGL(attn_kernel, dim3(640), dim3(256), 0, stream,
                     Qbf, Kbf, Vtile, partial, lpart);
  hipLaunchKernelGGL(reduce_kernel, dim3(256), dim3(256), 0, stream,
                     partial, lpart, out);
}

// Round 4
// 135.747 us; speedup vs baseline: 1.2249x; 1.0621x over previous
//
#include <hip/hip_runtime.h>
#include <stdint.h>

#define B_  4
#define T_  2048
#define C_  1024
#define D_  64

typedef float  f32x4  __attribute__((ext_vector_type(4)));
typedef float  f32x16 __attribute__((ext_vector_type(16)));
typedef short  s16x8  __attribute__((ext_vector_type(8)));

// softmax scale folded into Q-side weights/bias: 1/sqrt(64) * log2(e)
#define QSCALE 0.18033688011112042f

static __device__ __forceinline__ uint32_t f2bf(float f) {
  uint32_t u = __builtin_bit_cast(uint32_t, f);
  u += 0x7FFFu + ((u >> 16) & 1u);   // round-to-nearest-even
  return u >> 16;
}
static __device__ __forceinline__ uint32_t pack2bf(float a, float b) {
  return f2bf(a) | (f2bf(b) << 16);
}

// ---------------------------------------------------------------------------
// Kernel 1: pack W into MFMA-A-fragment order (R3-verified).
// Wp[g*8..g*8+7], g = (s32*12 + ntile)*64 + lane holds
// W^T[n = ntile*16 + (lane&15)][c = s32*32 + (lane>>4)*8 + j], j=0..7.
// ---------------------------------------------------------------------------
__global__ __launch_bounds__(256) void wconv_kernel(
    const float* __restrict__ Wq, const float* __restrict__ bq,
    const float* __restrict__ Wk, const float* __restrict__ bk,
    const float* __restrict__ Wv, const float* __restrict__ bv,
    uint16_t* __restrict__ Wp, float* __restrict__ biascat) {
  const int g = blockIdx.x * 256 + threadIdx.x;  // 0..24575
  const int s32   = g / 768;
  const int rem   = g - s32 * 768;
  const int ntile = rem >> 6;
  const int l     = rem & 63;
  const int mrow  = l & 15, u = l >> 4;
  const int n     = ntile * 16 + mrow;
  const int mat   = n >> 6, col = n & 63;
  const float* W  = (mat == 0) ? Wq : ((mat == 1) ? Wk : Wv);
  const float  s  = (mat == 0) ? QSCALE : 1.0f;
  const int c0    = s32 * 32 + u * 8;
  float v[8];
#pragma unroll
  for (int j = 0; j < 8; ++j) v[j] = W[(size_t)(c0 + j) * D_ + col] * s;
  uint4 st;
  st.x = pack2bf(v[0], v[1]);
  st.y = pack2bf(v[2], v[3]);
  st.z = pack2bf(v[4], v[5]);
  st.w = pack2bf(v[6], v[7]);
  *reinterpret_cast<uint4*>(Wp + (size_t)g * 8) = st;
  if (g < 192) {
    float bb;
    if (g < 64)       bb = bq[g] * QSCALE;
    else if (g < 128) bb = bk[g - 64];
    else              bb = bv[g - 128];
    biascat[g] = bb;
  }
}

// ---------------------------------------------------------------------------
// Kernel 2: QKV projection. BK=128 staging (8 barrier pairs, was 16) with
// cross-barrier load prefetch. MFMA mapping = R3-verified.
// ---------------------------------------------------------------------------
__global__ __launch_bounds__(256) void proj_kernel(
    const float* __restrict__ x, const uint16_t* __restrict__ Wp,
    const float* __restrict__ biascat,
    uint16_t* __restrict__ Qbf, uint16_t* __restrict__ Kbf,
    uint16_t* __restrict__ Vtile) {
  __shared__ __align__(16) uint16_t xt[16 * 132];       // 4224 B
  __shared__ __align__(16) uint16_t tbuf[4][16 * 28];   // 3584 B
  const int tid  = threadIdx.x;
  const int wave = tid >> 6;
  const int lane = tid & 63;
  const int mrow = lane & 15;
  const int u    = lane >> 4;
  const int m0   = blockIdx.x * 16;
  const int srow = tid >> 4, scol = tid & 15;

  const float* xg = x + (size_t)(m0 + srow) * C_ + scol * 4;

  f32x4 acc[3];
#pragma unroll
  for (int i = 0; i < 3; ++i)
#pragma unroll
    for (int r = 0; r < 4; ++r) acc[i][r] = 0.f;

  float4 xv0 = *reinterpret_cast<const float4*>(xg);
  float4 xv1 = *reinterpret_cast<const float4*>(xg + 64);

  for (int s = 0; s < 8; ++s) {
    uint2 w0, w1;
    w0.x = pack2bf(xv0.x, xv0.y);  w0.y = pack2bf(xv0.z, xv0.w);
    w1.x = pack2bf(xv1.x, xv1.y);  w1.y = pack2bf(xv1.z, xv1.w);
    __syncthreads();  // prior iter's frag reads done before overwrite
    *reinterpret_cast<uint2*>(&xt[srow * 132 + scol * 4])      = w0;
    *reinterpret_cast<uint2*>(&xt[srow * 132 + scol * 4 + 64]) = w1;
    __syncthreads();
    if (s < 7) {  // prefetch next BK=128 slab; hidden behind 12 MFMAs
      xv0 = *reinterpret_cast<const float4*>(xg + (s + 1) * 128);
      xv1 = *reinterpret_cast<const float4*>(xg + (s + 1) * 128 + 64);
    }
#pragma unroll
    for (int step = 0; step < 4; ++step) {
      const int s32 = s * 4 + step;
      s16x8 bf = *reinterpret_cast<const s16x8*>(&xt[mrow * 132 + step * 32 + u * 8]);
      const uint16_t* wb = Wp + ((size_t)(s32 * 12 + wave * 3) * 64 + lane) * 8;
      s16x8 a0 = *reinterpret_cast<const s16x8*>(wb);
      s16x8 a1 = *reinterpret_cast<const s16x8*>(wb + 64 * 8);
      s16x8 a2 = *reinterpret_cast<const s16x8*>(wb + 128 * 8);
      acc[0] = __builtin_amdgcn_mfma_f32_16x16x32_bf16(a0, bf, acc[0], 0, 0, 0);
      acc[1] = __builtin_amdgcn_mfma_f32_16x16x32_bf16(a1, bf, acc[1], 0, 0, 0);
      acc[2] = __builtin_amdgcn_mfma_f32_16x16x32_bf16(a2, bf, acc[2], 0, 0, 0);
    }
  }

  const int bb  = m0 >> 11;        // batch
  const int mm  = m0 & (T_ - 1);   // t offset within batch
#pragma unroll
  for (int nt = 0; nt < 3; ++nt) {
    const int nb = wave * 48 + nt * 16;
    uint16_t vals[4];
#pragma unroll
    for (int r = 0; r < 4; ++r)
      vals[r] = (uint16_t)f2bf(acc[nt][r] + biascat[nb + u * 4 + r]);
    if (nb >= 128) {
      // V -> tiled layout [b][t32][d][32t]
      const int tl   = mm >> 5;
      const int toff = (mm & 31) + mrow;
#pragma unroll
      for (int r = 0; r < 4; ++r) {
        int vrow = nb - 128 + u * 4 + r;
        Vtile[(((size_t)bb * 64 + tl) * 64 + vrow) * 32 + toff] = vals[r];
      }
    } else {
      // Q/K: per-wave LDS transpose, then 8B stores
#pragma unroll
      for (int r = 0; r < 4; ++r)
        tbuf[wave][mrow * 28 + u * 4 + r] = vals[r];
      const int row = lane >> 2, qtr = lane & 3;
      uint2 v = *reinterpret_cast<const uint2*>(&tbuf[wave][row * 28 + qtr * 4]);
      uint16_t* dst = (nb < 64) ? (Qbf + nb) : (Kbf + (nb - 64));
      *reinterpret_cast<uint2*>(dst + (size_t)(m0 + row) * D_ + qtr * 4) = v;
    }
  }
}

// ---------------------------------------------------------------------------
// Kernel 3: attention. Balanced jobs (verified decode), per-wave staged
// k-loop with register prefetch of the next tile, ZERO atomics: per-wave
// LDS partial dump (overlaid on dead K/V buffers) + barrier + b128 merge.
// Partial stored in raw MFMA slot space; reduce kernel decodes.
// slot(dm,r,hi,ql) = dm*1024 + r*64 + hi*32 + ql.
// ---------------------------------------------------------------------------
__global__ __launch_bounds__(256) void attn_kernel(
    const uint16_t* __restrict__ Qbf, const uint16_t* __restrict__ Kbf,
    const uint16_t* __restrict__ Vtile, float* __restrict__ partial,
    float* __restrict__ lpart) {
  __shared__ __align__(16) char smem[48768];
  uint16_t* qt_  = (uint16_t*)smem;            // 32*66*2   = 4224
  uint16_t* kt_  = (uint16_t*)(smem + 4224);   // 4*32*66*2 = 16896
  uint16_t* vt_  = (uint16_t*)(smem + 21120);  // 4*64*34*2 = 17408
  uint16_t* plds = (uint16_t*)(smem + 38528);  // 4*32*40*2 = 10240
  // phase-B overlay (after k-loop barrier):
  float* wpart = (float*)smem;                 // 4*2048*4  = 32768
  float* lw    = (float*)(smem + 32768);       // 128*4     = 512

  const int tid  = threadIdx.x;
  const int wave = tid >> 6;
  const int lane = tid & 63;
  const int ql   = lane & 31;
  const int hi   = lane >> 5;

  const int blk = blockIdx.x;
  const int b   = (blk & 7) >> 1;
  const int j   = 2 * (blk >> 3) + (blk & 1);

  int a_ = 0;
  while (8 * (a_ + 1) * (a_ + 2) <= j) ++a_;
  const int off = j - 8 * a_ * (a_ + 1);
  const int r_  = off / (a_ + 1);
  const int ch  = off - r_ * (a_ + 1);
  const int qt  = 16 * a_ + r_;
  const int c16 = ch * 16;
  const int qb  = qt * 32;
  const int tmax = min(c16 + 15, qt);
  const int pj  = b * 160 + j;

  const uint16_t* Qb = Qbf + (size_t)b * T_ * D_;
  const uint16_t* Kb = Kbf + (size_t)b * T_ * D_;

  // stage Q-tile (4KB contiguous), padded rows of 66
  {
    uint4 qv = *reinterpret_cast<const uint4*>(Qb + (size_t)qb * D_ + tid * 8);
    *reinterpret_cast<uint4*>(&qt_[(tid >> 3) * 66 + (tid & 7) * 8]) = qv;
  }
  __syncthreads();

  s16x8 qf[4];
#pragma unroll
  for (int c = 0; c < 4; ++c)
    qf[c] = *reinterpret_cast<const s16x8*>(&qt_[ql * 66 + c * 16 + hi * 8]);

  f32x16 aco[2];
#pragma unroll
  for (int i = 0; i < 2; ++i)
#pragma unroll
    for (int r = 0; r < 16; ++r) aco[i][r] = 0.f;
  float lacc = 0.f;

  uint16_t* ktw = kt_ + wave * 2112;
  uint16_t* vtw = vt_ + wave * 2176;

  const int t0 = c16 + wave;
  uint4 kv[4], vv[4];
  if (t0 <= tmax) {  // prologue load
    const uint16_t* kg = Kb + (size_t)(t0 * 32) * D_;
    const uint16_t* vg = Vtile + ((size_t)(b * 64 + t0) * 64) * 32;
#pragma unroll
    for (int jj = 0; jj < 4; ++jj)
      kv[jj] = *reinterpret_cast<const uint4*>(kg + jj * 512 + lane * 8);
#pragma unroll
    for (int jj = 0; jj < 4; ++jj)
      vv[jj] = *reinterpret_cast<const uint4*>(vg + jj * 512 + lane * 8);
  }

  for (int t = t0; t <= tmax; t += 4) {
    // stage current tile from regs (per-wave region, no barrier)
#pragma unroll
    for (int jj = 0; jj < 4; ++jj)
      *reinterpret_cast<uint4*>(
          &ktw[(8 * jj + (lane >> 3)) * 66 + (lane & 7) * 8]) = kv[jj];
#pragma unroll
    for (int jj = 0; jj < 4; ++jj)
      *reinterpret_cast<uint4*>(
          &vtw[(16 * jj + (lane >> 2)) * 34 + (lane & 3) * 8]) = vv[jj];
    // prefetch next tile (global latency hidden behind MFMA+exp2 below)
    if (t + 4 <= tmax) {
      const uint16_t* kg = Kb + (size_t)((t + 4) * 32) * D_;
      const uint16_t* vg = Vtile + ((size_t)(b * 64 + t + 4) * 64) * 32;
#pragma unroll
      for (int jj = 0; jj < 4; ++jj)
        kv[jj] = *reinterpret_cast<const uint4*>(kg + jj * 512 + lane * 8);
#pragma unroll
      for (int jj = 0; jj < 4; ++jj)
        vv[jj] = *reinterpret_cast<const uint4*>(vg + jj * 512 + lane * 8);
    }

    f32x16 sacc;
#pragma unroll
    for (int r = 0; r < 16; ++r) sacc[r] = 0.f;
#pragma unroll
    for (int c = 0; c < 4; ++c) {
      s16x8 kf = *reinterpret_cast<const s16x8*>(&ktw[ql * 66 + c * 16 + hi * 8]);
      sacc = __builtin_amdgcn_mfma_f32_32x32x16_bf16(kf, qf[c], sacc, 0, 0, 0);
    }

    if (t == qt) {  // diagonal tile: causal mask
#pragma unroll
      for (int r = 0; r < 16; ++r) {
        const int koff = (r & 3) + 8 * (r >> 2) + 4 * hi;
        sacc[r] = (koff > ql) ? -1e30f : sacc[r];
      }
    }
    float p[16];
#pragma unroll
    for (int r = 0; r < 16; ++r) p[r] = __builtin_amdgcn_exp2f(sacc[r]);
    float s01 = (p[0] + p[1]) + (p[2] + p[3]);
    float s23 = (p[4] + p[5]) + (p[6] + p[7]);
    float s45 = (p[8] + p[9]) + (p[10] + p[11]);
    float s67 = (p[12] + p[13]) + (p[14] + p[15]);
    lacc += (s01 + s23) + (s45 + s67);

    // P: C-layout -> A-layout via per-wave LDS (verified pattern)
#pragma unroll
    for (int g = 0; g < 4; ++g) {
      uint2 w;
      w.x = pack2bf(p[4 * g + 0], p[4 * g + 1]);
      w.y = pack2bf(p[4 * g + 2], p[4 * g + 3]);
      *reinterpret_cast<uint2*>(&plds[wave * 1280 + ql * 40 + 8 * g + 4 * hi]) = w;
    }
#pragma unroll
    for (int kc = 0; kc < 2; ++kc) {
      s16x8 pf = *reinterpret_cast<const s16x8*>(
          &plds[wave * 1280 + ql * 40 + kc * 16 + hi * 8]);
#pragma unroll
      for (int dm = 0; dm < 2; ++dm) {
        s16x8 vf = *reinterpret_cast<const s16x8*>(
            &vtw[(dm * 32 + ql) * 34 + kc * 16 + hi * 8]);
        aco[dm] = __builtin_amdgcn_mfma_f32_32x32x16_bf16(vf, pf, aco[dm], 0, 0, 0);
      }
    }
  }

  lacc += __shfl_xor(lacc, 32, 64);

  __syncthreads();  // all waves done with kt_/vt_ before overlay

  // wave-private dump: plain stores, contiguous 64 lanes per instr
#pragma unroll
  for (int dm = 0; dm < 2; ++dm)
#pragma unroll
    for (int r = 0; r < 16; ++r)
      wpart[wave * 2048 + dm * 1024 + r * 64 + hi * 32 + ql] = aco[dm][r];
  if (hi == 0) lw[wave * 32 + ql] = lacc;
  __syncthreads();

  // merge the 4 waves in slot space, write global partial (coalesced)
  {
    const int base = tid * 8;
    float4 s0 = {0.f, 0.f, 0.f, 0.f}, s1 = {0.f, 0.f, 0.f, 0.f};
#pragma unroll
    for (int w = 0; w < 4; ++w) {
      const float* p = wpart + w * 2048 + base;
      float4 a = *reinterpret_cast<const float4*>(p);
      float4 c = *reinterpret_cast<const float4*>(p + 4);
      s0.x += a.x; s0.y += a.y; s0.z += a.z; s0.w += a.w;
      s1.x += c.x; s1.y += c.y; s1.z += c.z; s1.w += c.w;
    }
    float* pp = partial + (size_t)pj * 2048 + base;
    *reinterpret_cast<float4*>(pp)     = s0;
    *reinterpret_cast<float4*>(pp + 4) = s1;
    if (tid < 32) {
      float ls = (lw[tid] + lw[32 + tid]) + (lw[64 + tid] + lw[96 + tid]);
      lpart[(size_t)pj * 32 + tid] = ls;
    }
  }
}

// ---------------------------------------------------------------------------
// Kernel 4: reduce chunk partials (slot space), decode slot -> (d,q),
// normalize, write out fp32 coalesced via LDS transpose.
// ---------------------------------------------------------------------------
__global__ __launch_bounds__(256) void reduce_kernel(
    const float* __restrict__ partial, const float* __restrict__ lpart,
    float* __restrict__ out) {
  __shared__ float trans[64 * 33];
  __shared__ float lbuf[32];
  const int blk = blockIdx.x;          // 256 = 4 b x 64 qt
  const int b   = blk >> 6;
  const int qt  = blk & 63;
  const int a_  = qt >> 4;
  const int nch = a_ + 1;
  const int pjb = b * 160 + 8 * a_ * (a_ + 1) + (qt & 15) * (a_ + 1);
  const int t   = threadIdx.x;

  if (t < 32) {
    float s = 0.f;
    for (int c = 0; c < nch; ++c) s += lpart[(size_t)(pjb + c) * 32 + t];
    lbuf[t] = 1.0f / s;
  }

  const int base = t * 8;
  float4 s0 = {0.f, 0.f, 0.f, 0.f}, s1 = {0.f, 0.f, 0.f, 0.f};
  for (int c = 0; c < nch; ++c) {
    const float* p = partial + (size_t)(pjb + c) * 2048 + base;
    float4 a = *reinterpret_cast<const float4*>(p);
    float4 d = *reinterpret_cast<const float4*>(p + 4);
    s0.x += a.x; s0.y += a.y; s0.z += a.z; s0.w += a.w;
    s1.x += d.x; s1.y += d.y; s1.z += d.z; s1.w += d.w;
  }
  // slot = dm*1024 + r*64 + hi*32 + ql; all 8 share (dm,r,hi)
  const int dm = base >> 10, r = (base >> 6) & 15, hi = (base >> 5) & 1;
  const int ql0 = base & 31;
  const int d = dm * 32 + (r & 3) + 8 * (r >> 2) + 4 * hi;
  float* tr = &trans[d * 33 + ql0];
  tr[0] = s0.x; tr[1] = s0.y; tr[2] = s0.z; tr[3] = s0.w;
  tr[4] = s1.x; tr[5] = s1.y; tr[6] = s1.z; tr[7] = s1.w;
  __syncthreads();

  const int q  = t >> 3;
  const int dg = (t & 7) * 8;
  const float rinv = lbuf[q];
  float4 o0, o1;
  o0.x = trans[(dg + 0) * 33 + q] * rinv;
  o0.y = trans[(dg + 1) * 33 + q] * rinv;
  o0.z = trans[(dg + 2) * 33 + q] * rinv;
  o0.w = trans[(dg + 3) * 33 + q] * rinv;
  o1.x = trans[(dg + 4) * 33 + q] * rinv;
  o1.y = trans[(dg + 5) * 33 + q] * rinv;
  o1.z = trans[(dg + 6) * 33 + q] * rinv;
  o1.w = trans[(dg + 7) * 33 + q] * rinv;
  float* op = out + ((size_t)(b * T_ + qt * 32 + q)) * D_ + dg;
  *reinterpret_cast<float4*>(op)     = o0;
  *reinterpret_cast<float4*>(op + 4) = o1;
}

// ---------------------------------------------------------------------------
extern "C" void kernel_launch(void* const* d_in, const int* in_sizes, int n_in,
                              void* d_out, int out_size, void* d_ws, size_t ws_size,
                              hipStream_t stream) {
  (void)in_sizes; (void)n_in; (void)out_size; (void)ws_size;
  const float* x  = (const float*)d_in[0];
  const float* Wq = (const float*)d_in[1];
  const float* bq = (const float*)d_in[2];
  const float* Wk = (const float*)d_in[3];
  const float* bk = (const float*)d_in[4];
  const float* Wv = (const float*)d_in[5];
  const float* bv = (const float*)d_in[6];
  float* out = (float*)d_out;

  char* ws = (char*)d_ws;
  uint16_t* Wp      = (uint16_t*)(ws);                 // 393,216 B
  float*    biascat = (float*)(ws + 393216);           // 1,024 B (768 used)
  uint16_t* Qbf     = (uint16_t*)(ws + 394240);        // 1,048,576 B
  uint16_t* Kbf     = (uint16_t*)(ws + 1442816);       // 1,048,576 B
  uint16_t* Vtile   = (uint16_t*)(ws + 2491392);       // 1,048,576 B
  float*    partial = (float*)(ws + 3539968);          // 5,242,880 B
  float*    lpart   = (float*)(ws + 8782848);          // 81,920 B

  hipLaunchKernelGGL(wconv_kernel, dim3(96), dim3(256), 0, stream,
                     Wq, bq, Wk, bk, Wv, bv, Wp, biascat);
  hipLaunchKernelGGL(proj_kernel, dim3(512), dim3(256), 0, stream,
                     x, Wp, biascat, Qbf, Kbf, Vtile);
  hipLaunchKernelGGL(attn_kernel, dim3(640), dim3(256), 0, stream,
                     Qbf, Kbf, Vtile, partial, lpart);
  hipLaunchKernelGGL(reduce_kernel, dim3(256), dim3(256), 0, stream,
                     partial, lpart, out);
}

// Round 5
// 110.795 us; speedup vs baseline: 1.5007x; 1.2252x over previous
//
#include <hip/hip_runtime.h>
#include <stdint.h>

#define B_  4
#define T_  2048
#define C_  1024
#define D_  64

typedef float  f32x4  __attribute__((ext_vector_type(4)));
typedef float  f32x16 __attribute__((ext_vector_type(16)));
typedef short  s16x8  __attribute__((ext_vector_type(8)));

// softmax scale folded into Q-side weights/bias: 1/sqrt(64) * log2(e)
#define QSCALE 0.18033688011112042f

static __device__ __forceinline__ uint32_t f2bf(float f) {
  uint32_t u = __builtin_bit_cast(uint32_t, f);
  u += 0x7FFFu + ((u >> 16) & 1u);   // round-to-nearest-even
  return u >> 16;
}
static __device__ __forceinline__ uint32_t pack2bf(float a, float b) {
  return f2bf(a) | (f2bf(b) << 16);
}

// ---------------------------------------------------------------------------
// Kernel 1: pack W into MFMA-A-fragment order (verified R3/R4).
// ---------------------------------------------------------------------------
__global__ __launch_bounds__(256) void wconv_kernel(
    const float* __restrict__ Wq, const float* __restrict__ bq,
    const float* __restrict__ Wk, const float* __restrict__ bk,
    const float* __restrict__ Wv, const float* __restrict__ bv,
    uint16_t* __restrict__ Wp, float* __restrict__ biascat) {
  const int g = blockIdx.x * 256 + threadIdx.x;  // 0..24575
  const int s32   = g / 768;
  const int rem   = g - s32 * 768;
  const int ntile = rem >> 6;
  const int l     = rem & 63;
  const int mrow  = l & 15, u = l >> 4;
  const int n     = ntile * 16 + mrow;
  const int mat   = n >> 6, col = n & 63;
  const float* W  = (mat == 0) ? Wq : ((mat == 1) ? Wk : Wv);
  const float  s  = (mat == 0) ? QSCALE : 1.0f;
  const int c0    = s32 * 32 + u * 8;
  float v[8];
#pragma unroll
  for (int j = 0; j < 8; ++j) v[j] = W[(size_t)(c0 + j) * D_ + col] * s;
  uint4 st;
  st.x = pack2bf(v[0], v[1]);
  st.y = pack2bf(v[2], v[3]);
  st.z = pack2bf(v[4], v[5]);
  st.w = pack2bf(v[6], v[7]);
  *reinterpret_cast<uint4*>(Wp + (size_t)g * 8) = st;
  if (g < 192) {
    float bb;
    if (g < 64)       bb = bq[g] * QSCALE;
    else if (g < 128) bb = bk[g - 64];
    else              bb = bv[g - 128];
    biascat[g] = bb;
  }
}

// ---------------------------------------------------------------------------
// Kernel 2: QKV projection. Double-buffered x slabs (BK=128): ONE barrier per
// slab; global prefetch overlaps MFMA. MFMA mapping verified R3/R4.
// ---------------------------------------------------------------------------
__global__ __launch_bounds__(256) void proj_kernel(
    const float* __restrict__ x, const uint16_t* __restrict__ Wp,
    const float* __restrict__ biascat,
    uint16_t* __restrict__ Qbf, uint16_t* __restrict__ Kbf,
    uint16_t* __restrict__ Vtile) {
  __shared__ __align__(16) uint16_t xt[2][16 * 132];    // 8448 B
  __shared__ __align__(16) uint16_t tbuf[4][16 * 28];   // 3584 B
  const int tid  = threadIdx.x;
  const int wave = tid >> 6;
  const int lane = tid & 63;
  const int mrow = lane & 15;
  const int u    = lane >> 4;
  const int m0   = blockIdx.x * 16;
  const int srow = tid >> 4, scol = tid & 15;

  const float* xg = x + (size_t)(m0 + srow) * C_ + scol * 4;

  f32x4 acc[3];
#pragma unroll
  for (int i = 0; i < 3; ++i)
#pragma unroll
    for (int r = 0; r < 4; ++r) acc[i][r] = 0.f;

  // slab 0: load + store to xt[0]
  float4 xv0 = *reinterpret_cast<const float4*>(xg);
  float4 xv1 = *reinterpret_cast<const float4*>(xg + 64);
  {
    uint2 w0, w1;
    w0.x = pack2bf(xv0.x, xv0.y);  w0.y = pack2bf(xv0.z, xv0.w);
    w1.x = pack2bf(xv1.x, xv1.y);  w1.y = pack2bf(xv1.z, xv1.w);
    *reinterpret_cast<uint2*>(&xt[0][srow * 132 + scol * 4])      = w0;
    *reinterpret_cast<uint2*>(&xt[0][srow * 132 + scol * 4 + 64]) = w1;
  }
  __syncthreads();

  for (int s = 0; s < 8; ++s) {
    const int cur = s & 1;
    if (s < 7) {  // prefetch next slab (overlaps the 12 MFMAs below)
      xv0 = *reinterpret_cast<const float4*>(xg + (s + 1) * 128);
      xv1 = *reinterpret_cast<const float4*>(xg + (s + 1) * 128 + 64);
    }
#pragma unroll
    for (int step = 0; step < 4; ++step) {
      const int s32 = s * 4 + step;
      s16x8 bf = *reinterpret_cast<const s16x8*>(
          &xt[cur][mrow * 132 + step * 32 + u * 8]);
      const uint16_t* wb = Wp + ((size_t)(s32 * 12 + wave * 3) * 64 + lane) * 8;
      s16x8 a0 = *reinterpret_cast<const s16x8*>(wb);
      s16x8 a1 = *reinterpret_cast<const s16x8*>(wb + 64 * 8);
      s16x8 a2 = *reinterpret_cast<const s16x8*>(wb + 128 * 8);
      acc[0] = __builtin_amdgcn_mfma_f32_16x16x32_bf16(a0, bf, acc[0], 0, 0, 0);
      acc[1] = __builtin_amdgcn_mfma_f32_16x16x32_bf16(a1, bf, acc[1], 0, 0, 0);
      acc[2] = __builtin_amdgcn_mfma_f32_16x16x32_bf16(a2, bf, acc[2], 0, 0, 0);
    }
    if (s < 7) {  // write next slab to the other buffer, single barrier
      uint2 w0, w1;
      w0.x = pack2bf(xv0.x, xv0.y);  w0.y = pack2bf(xv0.z, xv0.w);
      w1.x = pack2bf(xv1.x, xv1.y);  w1.y = pack2bf(xv1.z, xv1.w);
      *reinterpret_cast<uint2*>(&xt[cur ^ 1][srow * 132 + scol * 4])      = w0;
      *reinterpret_cast<uint2*>(&xt[cur ^ 1][srow * 132 + scol * 4 + 64]) = w1;
      __syncthreads();
    }
  }

  const int bb  = m0 >> 11;        // batch
  const int mm  = m0 & (T_ - 1);   // t offset within batch
#pragma unroll
  for (int nt = 0; nt < 3; ++nt) {
    const int nb = wave * 48 + nt * 16;
    uint16_t vals[4];
#pragma unroll
    for (int r = 0; r < 4; ++r)
      vals[r] = (uint16_t)f2bf(acc[nt][r] + biascat[nb + u * 4 + r]);
    if (nb >= 128) {
      // V -> tiled layout [b][t32][d][32t]
      const int tl   = mm >> 5;
      const int toff = (mm & 31) + mrow;
#pragma unroll
      for (int r = 0; r < 4; ++r) {
        int vrow = nb - 128 + u * 4 + r;
        Vtile[(((size_t)bb * 64 + tl) * 64 + vrow) * 32 + toff] = vals[r];
      }
    } else {
      // Q/K: per-wave LDS transpose, then 8B stores
#pragma unroll
      for (int r = 0; r < 4; ++r)
        tbuf[wave][mrow * 28 + u * 4 + r] = vals[r];
      const int row = lane >> 2, qtr = lane & 3;
      uint2 v = *reinterpret_cast<const uint2*>(&tbuf[wave][row * 28 + qtr * 4]);
      uint16_t* dst = (nb < 64) ? (Qbf + nb) : (Kbf + (nb - 64));
      *reinterpret_cast<uint2*>(dst + (size_t)(m0 + row) * D_ + qtr * 4) = v;
    }
  }
}

// ---------------------------------------------------------------------------
// Kernel 3: attention. ZERO LDS in the k-loop: K/V/Q fragments loaded direct
// from global in fragment order (register double-buffered); P C-layout ->
// B-frag via 4 shfl_xor(32) + cndmasks (q-column stays in lane pair ql,ql+32).
// Epilogue: wave-private LDS dump + merge (verified R4). slot space:
// slot(dm,r,hi,ql) = dm*1024 + r*64 + hi*32 + ql.
// ---------------------------------------------------------------------------
__global__ __launch_bounds__(256) void attn_kernel(
    const uint16_t* __restrict__ Qbf, const uint16_t* __restrict__ Kbf,
    const uint16_t* __restrict__ Vtile, float* __restrict__ partial,
    float* __restrict__ lpart) {
  __shared__ float wpart[4 * 2048];   // 32768 B
  __shared__ float lw[128];           // 512 B

  const int tid  = threadIdx.x;
  const int wave = tid >> 6;
  const int lane = tid & 63;
  const int ql   = lane & 31;
  const int hi   = lane >> 5;

  const int blk = blockIdx.x;
  const int b   = (blk & 7) >> 1;
  const int j   = 2 * (blk >> 3) + (blk & 1);

  int a_ = 0;
  while (8 * (a_ + 1) * (a_ + 2) <= j) ++a_;
  const int off = j - 8 * a_ * (a_ + 1);
  const int r_  = off / (a_ + 1);
  const int ch  = off - r_ * (a_ + 1);
  const int qt  = 16 * a_ + r_;
  const int c16 = ch * 16;
  const int qb  = qt * 32;
  const int tmax = min(c16 + 15, qt);
  const int pj  = b * 160 + j;

  const uint16_t* Qb = Qbf + (size_t)b * T_ * D_;
  const uint16_t* Kb = Kbf + (size_t)b * T_ * D_;

  // Q fragments direct from global (8x16B/lane, L1-absorbed)
  const uint16_t* qg = Qb + (size_t)(qb + ql) * D_ + hi * 8;
  s16x8 qf[4];
#pragma unroll
  for (int c = 0; c < 4; ++c)
    qf[c] = *reinterpret_cast<const s16x8*>(qg + c * 16);

  f32x16 aco[2];
#pragma unroll
  for (int i = 0; i < 2; ++i)
#pragma unroll
    for (int r = 0; r < 16; ++r) aco[i][r] = 0.f;
  float lacc = 0.f;

  // fragment-order tile load: kf[c]=K[t*32+ql][c*16+hi*8+..], vf[dm*2+kc]
  auto load_tile = [&](int t, s16x8* kf, s16x8* vf) {
    const uint16_t* kg = Kb + (size_t)(t * 32 + ql) * D_ + hi * 8;
#pragma unroll
    for (int c = 0; c < 4; ++c)
      kf[c] = *reinterpret_cast<const s16x8*>(kg + c * 16);
    const uint16_t* vg = Vtile + ((size_t)(b * 64 + t) * 64 + ql) * 32 + hi * 8;
    vf[0] = *reinterpret_cast<const s16x8*>(vg);              // dm0 kc0
    vf[1] = *reinterpret_cast<const s16x8*>(vg + 16);         // dm0 kc1
    vf[2] = *reinterpret_cast<const s16x8*>(vg + 1024);       // dm1 kc0
    vf[3] = *reinterpret_cast<const s16x8*>(vg + 1024 + 16);  // dm1 kc1
  };

  auto compute = [&](int t, const s16x8* kf, const s16x8* vf) {
    f32x16 sacc;
#pragma unroll
    for (int r = 0; r < 16; ++r) sacc[r] = 0.f;
#pragma unroll
    for (int c = 0; c < 4; ++c)
      sacc = __builtin_amdgcn_mfma_f32_32x32x16_bf16(kf[c], qf[c], sacc, 0, 0, 0);
    if (t == qt) {  // diagonal tile: causal mask
#pragma unroll
      for (int r = 0; r < 16; ++r) {
        const int koff = (r & 3) + 8 * (r >> 2) + 4 * hi;
        sacc[r] = (koff > ql) ? -1e30f : sacc[r];
      }
    }
    float p[16];
#pragma unroll
    for (int r = 0; r < 16; ++r) p[r] = __builtin_amdgcn_exp2f(sacc[r]);
    float s01 = (p[0] + p[1]) + (p[2] + p[3]);
    float s23 = (p[4] + p[5]) + (p[6] + p[7]);
    float s45 = (p[8] + p[9]) + (p[10] + p[11]);
    float s67 = (p[12] + p[13]) + (p[14] + p[15]);
    lacc += (s01 + s23) + (s45 + s67);

    // P -> B-frag via lane-pair exchange (ql <-> ql+32), no LDS round-trip.
    // lane(ql,hi) reg r = P[ql][k=(r&3)+8*(r>>2)+4*hi]
    uint32_t A0 = pack2bf(p[0], p[1]),  A1 = pack2bf(p[2], p[3]);
    uint32_t B0 = pack2bf(p[4], p[5]),  B1 = pack2bf(p[6], p[7]);
    uint32_t C0 = pack2bf(p[8], p[9]),  C1 = pack2bf(p[10], p[11]);
    uint32_t D0 = pack2bf(p[12], p[13]), D1 = pack2bf(p[14], p[15]);
    uint32_t r0 = (uint32_t)__shfl_xor((int)(hi ? A0 : B0), 32, 64);
    uint32_t r1 = (uint32_t)__shfl_xor((int)(hi ? A1 : B1), 32, 64);
    uint32_t r2 = (uint32_t)__shfl_xor((int)(hi ? C0 : D0), 32, 64);
    uint32_t r3 = (uint32_t)__shfl_xor((int)(hi ? C1 : D1), 32, 64);
    union { uint32_t u[4]; s16x8 v; } pf0, pf1;
    pf0.u[0] = hi ? r0 : A0;  pf0.u[1] = hi ? r1 : A1;
    pf0.u[2] = hi ? B0 : r0;  pf0.u[3] = hi ? B1 : r1;
    pf1.u[0] = hi ? r2 : C0;  pf1.u[1] = hi ? r3 : C1;
    pf1.u[2] = hi ? D0 : r2;  pf1.u[3] = hi ? D1 : r3;
    aco[0] = __builtin_amdgcn_mfma_f32_32x32x16_bf16(vf[0], pf0.v, aco[0], 0, 0, 0);
    aco[1] = __builtin_amdgcn_mfma_f32_32x32x16_bf16(vf[2], pf0.v, aco[1], 0, 0, 0);
    aco[0] = __builtin_amdgcn_mfma_f32_32x32x16_bf16(vf[1], pf1.v, aco[0], 0, 0, 0);
    aco[1] = __builtin_amdgcn_mfma_f32_32x32x16_bf16(vf[3], pf1.v, aco[1], 0, 0, 0);
  };

  // register-double-buffered k-loop (<=4 tiles per wave)
  {
    int t = c16 + wave;
    if (t <= tmax) {
      s16x8 kfA[4], vfA[4], kfB[4], vfB[4];
      load_tile(t, kfA, vfA);
      while (true) {
        int tn = t + 4;
        if (tn <= tmax) load_tile(tn, kfB, vfB);
        compute(t, kfA, vfA);
        if (tn > tmax) break;
        t = tn; tn = t + 4;
        if (tn <= tmax) load_tile(tn, kfA, vfA);
        compute(t, kfB, vfB);
        if (tn > tmax) break;
        t = tn;
      }
    }
  }

  lacc += __shfl_xor(lacc, 32, 64);

  // wave-private dump + merge (verified R4)
#pragma unroll
  for (int dm = 0; dm < 2; ++dm)
#pragma unroll
    for (int r = 0; r < 16; ++r)
      wpart[wave * 2048 + dm * 1024 + r * 64 + hi * 32 + ql] = aco[dm][r];
  if (hi == 0) lw[wave * 32 + ql] = lacc;
  __syncthreads();

  {
    const int base = tid * 8;
    float4 s0 = {0.f, 0.f, 0.f, 0.f}, s1 = {0.f, 0.f, 0.f, 0.f};
#pragma unroll
    for (int w = 0; w < 4; ++w) {
      const float* p = wpart + w * 2048 + base;
      float4 a = *reinterpret_cast<const float4*>(p);
      float4 c = *reinterpret_cast<const float4*>(p + 4);
      s0.x += a.x; s0.y += a.y; s0.z += a.z; s0.w += a.w;
      s1.x += c.x; s1.y += c.y; s1.z += c.z; s1.w += c.w;
    }
    float* pp = partial + (size_t)pj * 2048 + base;
    *reinterpret_cast<float4*>(pp)     = s0;
    *reinterpret_cast<float4*>(pp + 4) = s1;
    if (tid < 32) {
      float ls = (lw[tid] + lw[32 + tid]) + (lw[64 + tid] + lw[96 + tid]);
      lpart[(size_t)pj * 32 + tid] = ls;
    }
  }
}

// ---------------------------------------------------------------------------
// Kernel 4: reduce chunk partials (slot space), decode, normalize, write out.
// ---------------------------------------------------------------------------
__global__ __launch_bounds__(256) void reduce_kernel(
    const float* __restrict__ partial, const float* __restrict__ lpart,
    float* __restrict__ out) {
  __shared__ float trans[64 * 33];
  __shared__ float lbuf[32];
  const int blk = blockIdx.x;          // 256 = 4 b x 64 qt
  const int b   = blk >> 6;
  const int qt  = blk & 63;
  const int a_  = qt >> 4;
  const int nch = a_ + 1;
  const int pjb = b * 160 + 8 * a_ * (a_ + 1) + (qt & 15) * (a_ + 1);
  const int t   = threadIdx.x;

  if (t < 32) {
    float s = 0.f;
    for (int c = 0; c < nch; ++c) s += lpart[(size_t)(pjb + c) * 32 + t];
    lbuf[t] = 1.0f / s;
  }

  const int base = t * 8;
  float4 s0 = {0.f, 0.f, 0.f, 0.f}, s1 = {0.f, 0.f, 0.f, 0.f};
  for (int c = 0; c < nch; ++c) {
    const float* p = partial + (size_t)(pjb + c) * 2048 + base;
    float4 a = *reinterpret_cast<const float4*>(p);
    float4 d = *reinterpret_cast<const float4*>(p + 4);
    s0.x += a.x; s0.y += a.y; s0.z += a.z; s0.w += a.w;
    s1.x += d.x; s1.y += d.y; s1.z += d.z; s1.w += d.w;
  }
  const int dm = base >> 10, r = (base >> 6) & 15, hi = (base >> 5) & 1;
  const int ql0 = base & 31;
  const int d = dm * 32 + (r & 3) + 8 * (r >> 2) + 4 * hi;
  float* tr = &trans[d * 33 + ql0];
  tr[0] = s0.x; tr[1] = s0.y; tr[2] = s0.z; tr[3] = s0.w;
  tr[4] = s1.x; tr[5] = s1.y; tr[6] = s1.z; tr[7] = s1.w;
  __syncthreads();

  const int q  = t >> 3;
  const int dg = (t & 7) * 8;
  const float rinv = lbuf[q];
  float4 o0, o1;
  o0.x = trans[(dg + 0) * 33 + q] * rinv;
  o0.y = trans[(dg + 1) * 33 + q] * rinv;
  o0.z = trans[(dg + 2) * 33 + q] * rinv;
  o0.w = trans[(dg + 3) * 33 + q] * rinv;
  o1.x = trans[(dg + 4) * 33 + q] * rinv;
  o1.y = trans[(dg + 5) * 33 + q] * rinv;
  o1.z = trans[(dg + 6) * 33 + q] * rinv;
  o1.w = trans[(dg + 7) * 33 + q] * rinv;
  float* op = out + ((size_t)(b * T_ + qt * 32 + q)) * D_ + dg;
  *reinterpret_cast<float4*>(op)     = o0;
  *reinterpret_cast<float4*>(op + 4) = o1;
}

// ---------------------------------------------------------------------------
extern "C" void kernel_launch(void* const* d_in, const int* in_sizes, int n_in,
                              void* d_out, int out_size, void* d_ws, size_t ws_size,
                              hipStream_t stream) {
  (void)in_sizes; (void)n_in; (void)out_size; (void)ws_size;
  const float* x  = (const float*)d_in[0];
  const float* Wq = (const float*)d_in[1];
  const float* bq = (const float*)d_in[2];
  const float* Wk = (const float*)d_in[3];
  const float* bk = (const float*)d_in[4];
  const float* Wv = (const float*)d_in[5];
  const float* bv = (const float*)d_in[6];
  float* out = (float*)d_out;

  char* ws = (char*)d_ws;
  uint16_t* Wp      = (uint16_t*)(ws);                 // 393,216 B
  float*    biascat = (float*)(ws + 393216);           // 1,024 B (768 used)
  uint16_t* Qbf     = (uint16_t*)(ws + 394240);        // 1,048,576 B
  uint16_t* Kbf     = (uint16_t*)(ws + 1442816);       // 1,048,576 B
  uint16_t* Vtile   = (uint16_t*)(ws + 2491392);       // 1,048,576 B
  float*    partial = (float*)(ws + 3539968);          // 5,242,880 B
  float*    lpart   = (float*)(ws + 8782848);          // 81,920 B

  hipLaunchKernelGGL(wconv_kernel, dim3(96), dim3(256), 0, stream,
                     Wq, bq, Wk, bk, Wv, bv, Wp, biascat);
  hipLaunchKernelGGL(proj_kernel, dim3(512), dim3(256), 0, stream,
                     x, Wp, biascat, Qbf, Kbf, Vtile);
  hipLaunchKernelGGL(attn_kernel, dim3(640), dim3(256), 0, stream,
                     Qbf, Kbf, Vtile, partial, lpart);
  hipLaunchKernelGGL(reduce_kernel, dim3(256), dim3(256), 0, stream,
                     partial, lpart, out);
}